// Round 9
// baseline (234.389 us; speedup 1.0000x reference)
//
#include <hip/hip_runtime.h>
#include <cstdint>
#include <cstddef>

typedef _Float16 f16;
typedef _Float16 f16x4 __attribute__((ext_vector_type(4)));
typedef _Float16 f16x8 __attribute__((ext_vector_type(8)));
typedef float    f32x4 __attribute__((ext_vector_type(4)));

#define NB 64
#define NN 262144   // 512*512

__device__ __forceinline__ void gload_lds16(const void* g, void* l) {
    __builtin_amdgcn_global_load_lds(
        (const __attribute__((address_space(1))) void*)g,
        (__attribute__((address_space(3))) void*)l, 16, 0, 0);
}

// Role-split prep, ILP-deep: grid 2048 (8 blocks/CU; each CU gets 4 colsum + 4 cvt).
// Blocks [0,1024): colsum partials — 16 independent f32x4 loads/thread, tree sum.
// Blocks [1024,2048): cvtX 8 units (16 f32x4 loads in flight); first 192 also transW.
__global__ __launch_bounds__(256, 4)
void k_pre(const float* __restrict__ X0, f16* __restrict__ X_h,
           const float* __restrict__ W1, const float* __restrict__ W2,
           const float* __restrict__ W3, f16* __restrict__ Wt,
           const float* __restrict__ adj, float* __restrict__ part) {
    __shared__ float t[64][65];
    const int bid = blockIdx.x, tid = threadIdx.x;

    if (bid < 1024) {
        // colsum partial: chunk = 16 rows, float4 columns.
        int b = bid >> 4;
        int rr0 = (bid & 15) * 32 + (tid >> 7) * 16;
        int c4 = (tid & 127) * 4;
        const float* ab = adj + (size_t)b * NN + (size_t)rr0 * 512 + c4;
        f32x4 v[16];
        #pragma unroll
        for (int i = 0; i < 16; ++i)
            v[i] = *(const f32x4*)(ab + (size_t)i * 512);
        f32x4 s = ((v[0] + v[1]) + (v[2] + v[3])) + ((v[4] + v[5]) + (v[6] + v[7]))
                + ((v[8] + v[9]) + (v[10] + v[11])) + ((v[12] + v[13]) + (v[14] + v[15]));
        int ch2 = (bid & 15) * 2 + (tid >> 7);
        *(f32x4*)&part[((size_t)b * 32 + ch2) * 512 + c4] = s;
    } else {
        // cvtX: 8 units of (256 thr x 8 floats); all 16 loads issued before stores
        int cb = bid - 1024;                      // 0..1023
        float4 v[16];
        #pragma unroll
        for (int s = 0; s < 8; ++s) {
            size_t i = (((size_t)(cb + 1024 * s)) * 256 + tid) * 8;
            v[2 * s]     = *(const float4*)(X0 + i);
            v[2 * s + 1] = *(const float4*)(X0 + i + 4);
        }
        #pragma unroll
        for (int s = 0; s < 8; ++s) {
            size_t i = (((size_t)(cb + 1024 * s)) * 256 + tid) * 8;
            f16x8 o;
            o[0] = (f16)v[2*s].x;   o[1] = (f16)v[2*s].y;
            o[2] = (f16)v[2*s].z;   o[3] = (f16)v[2*s].w;
            o[4] = (f16)v[2*s+1].x; o[5] = (f16)v[2*s+1].y;
            o[6] = (f16)v[2*s+1].z; o[7] = (f16)v[2*s+1].w;
            *(f16x8*)(X_h + i) = o;
        }
        if (cb < 192) {
            // transW: Wt[z][d][k] = f16(64 * Wz[k][d])
            int z = cb >> 6, rem = cb & 63;
            const float* W = z == 0 ? W1 : (z == 1 ? W2 : W3);
            f16* out = Wt + (size_t)z * NN;
            int k0 = (rem >> 3) * 64, d0 = (rem & 7) * 64;
            int c = tid & 63, r4 = tid >> 6;
            #pragma unroll
            for (int s = 0; s < 16; ++s) {
                int rr = r4 + s * 4;
                t[rr][c] = W[(size_t)(k0 + rr) * 512 + d0 + c];
            }
            __syncthreads();
            int kq = (tid & 15) * 4;
            int db = tid >> 4;
            #pragma unroll
            for (int s = 0; s < 4; ++s) {
                int dd = db + s * 16;
                f16x4 o;
                #pragma unroll
                for (int q = 0; q < 4; ++q)
                    o[q] = (f16)(64.f * t[kq + q][dd]);
                *(f16x4*)&out[(size_t)(d0 + dd) * 512 + k0 + kq] = o;
            }
        }
    }
}

// A_h[b][i][j] = f16( 16 * r[b][i] * adj[b][j][i] * r[b][j] ),
// r finished inline from the 32 colsum partials; tile loads via float4.
__global__ void k_makeA(const float* __restrict__ adj, const float* __restrict__ part,
                        f16* __restrict__ A_h) {
    __shared__ float t[64][68];                    // stride 68: 16B-aligned float4 cols
    __shared__ float ri_s[64], rj_s[64];
    const int tid = threadIdx.x;
    int b = blockIdx.z;
    int i0 = blockIdx.y * 64, j0 = blockIdx.x * 64;
    const float* ab = adj + (size_t)b * NN;
    int trow = tid >> 4;                           // 0..15
    int tc4  = (tid & 15) * 4;
    #pragma unroll
    for (int s = 0; s < 4; ++s) {
        int rr = trow + s * 16;                    // j-index
        *(f32x4*)&t[rr][tc4] = *(const f32x4*)&ab[(size_t)(j0 + rr) * 512 + i0 + tc4];
    }
    if (tid < 128) {
        int col = tid < 64 ? i0 + tid : j0 + tid - 64;
        const float* p = part + (size_t)b * 32 * 512 + col;
        float s = 0.f;
        #pragma unroll
        for (int ch = 0; ch < 32; ++ch) s += p[ch * 512];
        float rv = (s > 0.f) ? rsqrtf(s) : 0.f;
        if (tid < 64) ri_s[tid] = rv;
        else          rj_s[tid - 64] = rv;
    }
    __syncthreads();
    f16* Ab = A_h + (size_t)b * NN;
    int jq = (tid & 15) * 4;
    int ib = tid >> 4;
    #pragma unroll
    for (int s = 0; s < 4; ++s) {
        int ii = ib + s * 16;
        float ri = 16.f * ri_s[ii];
        f16x4 o;
        #pragma unroll
        for (int q = 0; q < 4; ++q)
            o[q] = (f16)(ri * t[jq + q][ii] * rj_s[jq + q]);
        *(f16x4*)&Ab[(size_t)(i0 + ii) * 512 + j0 + jq] = o;
    }
}

// C[m][n] = sum_k P[m][k] * Qt[n][k];  out Ct[n][m] = act(C*iscale + bias[m]) * oscale
// 128x128 tile, BK=64, 4 waves (2Mx2N), 64 KiB LDS -> 2 WG/CU,
// two-barrier counted-vmcnt(8) pipeline, both-sides XOR slot swizzle.
template<bool BIAS, bool RELU, bool OUTF32>
__global__ __launch_bounds__(256, 2)
void gemm_tn_ct(const f16* __restrict__ P, size_t pstr,
                const f16* __restrict__ Qt, size_t qstr,
                void* __restrict__ Cout, size_t cstr,
                const float* __restrict__ bias, float iscale, float oscale) {
    __shared__ __align__(16) f16 Plds[2][8192];   // 2 x 128x64 f16 = 32 KiB
    __shared__ __align__(16) f16 Qlds[2][8192];   // 32 KiB

    const int tid  = threadIdx.x;
    const int lane = tid & 63;
    const int wid  = tid >> 6;
    const int wm   = wid >> 1;
    const int wn   = wid & 1;

    const int wg  = blockIdx.x;
    const int swz = (wg & 7) * 128 + (wg >> 3);
    const int b   = swz >> 4;
    const int tt  = swz & 15;
    const int m0  = (tt >> 2) * 128;
    const int n0  = (tt & 3) * 128;

    const f16* Pb = P + (size_t)b * pstr;
    const f16* Qb = Qt + (size_t)b * qstr;

    const int srow = tid >> 3;                      // 0..31
    const int sswz = (tid & 7) ^ (srow & 7);        // swizzled source slot

    const int fr  = lane & 15;
    const int fs  = lane >> 4;
    const int fx  = fr & 7;

    auto stage = [&](const f16* __restrict__ Gb, int row0, f16* lds, int k0) {
        #pragma unroll
        for (int r = 0; r < 4; ++r) {
            const f16* src = Gb + (size_t)(row0 + r * 32 + srow) * 512 + k0 + sswz * 8;
            gload_lds16(src, lds + r * 2048 + tid * 8);
        }
    };

    f32x4 acc[4][4] = {};

    stage(Pb, m0, &Plds[0][0], 0);
    stage(Qb, n0, &Qlds[0][0], 0);

    for (int t = 0; t < 8; ++t) {
        const int nb = t & 1;
        if (t < 7) {
            stage(Pb, m0, &Plds[nb ^ 1][0], (t + 1) * 64);
            stage(Qb, n0, &Qlds[nb ^ 1][0], (t + 1) * 64);
            asm volatile("s_waitcnt vmcnt(8)" ::: "memory");   // tile t landed; t+1 in flight
        } else {
            asm volatile("s_waitcnt vmcnt(0)" ::: "memory");
        }
        __builtin_amdgcn_s_barrier();

        const f16* Pl = &Plds[nb][0];
        const f16* Ql = &Qlds[nb][0];
        #pragma unroll
        for (int krep = 0; krep < 2; ++krep) {
            const int sp = ((fs + krep * 4) ^ fx) * 8;
            f16x8 af[4], bf[4];
            #pragma unroll
            for (int mi = 0; mi < 4; ++mi)
                af[mi] = *(const f16x8*)&Pl[(wm * 64 + mi * 16 + fr) * 64 + sp];
            #pragma unroll
            for (int ni = 0; ni < 4; ++ni)
                bf[ni] = *(const f16x8*)&Ql[(wn * 64 + ni * 16 + fr) * 64 + sp];
            __builtin_amdgcn_s_setprio(1);
            #pragma unroll
            for (int mi = 0; mi < 4; ++mi)
                #pragma unroll
                for (int ni = 0; ni < 4; ++ni)
                    acc[mi][ni] = __builtin_amdgcn_mfma_f32_16x16x32_f16(
                        af[mi], bf[ni], acc[mi][ni], 0, 0, 0);
            __builtin_amdgcn_s_setprio(0);
        }
        asm volatile("s_waitcnt lgkmcnt(0)" ::: "memory");
        __builtin_amdgcn_sched_barrier(0);
        __builtin_amdgcn_s_barrier();
    }

    const int cmb = (lane >> 4) * 4;
    #pragma unroll
    for (int mi = 0; mi < 4; ++mi) {
        #pragma unroll
        for (int ni = 0; ni < 4; ++ni) {
            const int n = n0 + wn * 64 + ni * 16 + fr;
            const int m = m0 + wm * 64 + mi * 16 + cmb;
            float v[4];
            #pragma unroll
            for (int q = 0; q < 4; ++q) {
                float x = acc[mi][ni][q] * iscale;
                if (BIAS) x += bias[m + q];
                if (RELU) x = fmaxf(x, 0.f);
                v[q] = x * oscale;
            }
            if (OUTF32) {
                float* Cb = (float*)Cout + (size_t)b * cstr;
                f32x4 o; o[0] = v[0]; o[1] = v[1]; o[2] = v[2]; o[3] = v[3];
                *(f32x4*)&Cb[(size_t)n * 512 + m] = o;
            } else {
                f16* Cb = (f16*)Cout + (size_t)b * cstr;
                f16x4 o; o[0] = (f16)v[0]; o[1] = (f16)v[1]; o[2] = (f16)v[2]; o[3] = (f16)v[3];
                *(f16x4*)&Cb[(size_t)n * 512 + m] = o;
            }
        }
    }
}

extern "C" void kernel_launch(void* const* d_in, const int* in_sizes, int n_in,
                              void* d_out, int out_size, void* d_ws, size_t ws_size,
                              hipStream_t stream) {
    const float* X0  = (const float*)d_in[0];
    const float* adj = (const float*)d_in[1];
    const float* W1  = (const float*)d_in[2];
    const float* b1  = (const float*)d_in[3];
    const float* W2  = (const float*)d_in[4];
    const float* b2  = (const float*)d_in[5];
    const float* W3  = (const float*)d_in[6];
    const float* b3  = (const float*)d_in[7];

    uint8_t* ws = (uint8_t*)d_ws;
    f16* Wt1 = (f16*)(ws + 131072);                        // 3 x 512 KiB
    f16* Wt2 = Wt1 + NN;
    f16* Wt3 = Wt2 + NN;
    f16* A_h = (f16*)(ws + 131072 + (size_t)3 * NN * 2);   // 32 MiB
    f16* X_h = A_h + (size_t)NB * NN;                      // 32 MiB (X / activations)
    f16* S_t = X_h + (size_t)NB * NN;                      // 32 MiB
    float* part = (float*)S_t;   // 64*32*512*4 = 4 MiB, aliased (S_t written after makeA)

    k_pre  <<<dim3(2048),     dim3(256), 0, stream>>>(X0, X_h, W1, W2, W3, Wt1, adj, part);
    k_makeA<<<dim3(8, 8, NB), dim3(256), 0, stream>>>(adj, part, A_h);

    dim3 gg(1024), gb(256);
    // scales: X stored x1 (layer1) / x256 (layer3 input); W stored x64; A stored x16.
    gemm_tn_ct<false, false, false><<<gg, gb, 0, stream>>>(X_h, (size_t)NN, Wt1, (size_t)0,  S_t, (size_t)NN, nullptr, 1.f, 1.f / 64.f);
    gemm_tn_ct<true,  true,  false><<<gg, gb, 0, stream>>>(S_t, (size_t)NN, A_h, (size_t)NN, X_h, (size_t)NN, b1, 1.f / 16.f, 1.f);
    gemm_tn_ct<false, false, false><<<gg, gb, 0, stream>>>(X_h, (size_t)NN, Wt2, (size_t)0,  S_t, (size_t)NN, nullptr, 1.f, 4.f);
    gemm_tn_ct<true,  true,  false><<<gg, gb, 0, stream>>>(S_t, (size_t)NN, A_h, (size_t)NN, X_h, (size_t)NN, b2, 1.f / 4096.f, 256.f);
    gemm_tn_ct<false, false, false><<<gg, gb, 0, stream>>>(X_h, (size_t)NN, Wt3, (size_t)0,  S_t, (size_t)NN, nullptr, 1.f, 1.f / 64.f);
    gemm_tn_ct<true,  false, true ><<<gg, gb, 0, stream>>>(S_t, (size_t)NN, A_h, (size_t)NN, d_out, (size_t)NN, b3, 1.f / 4096.f, 1.f);
}

// Round 10
// 227.380 us; speedup vs baseline: 1.0308x; 1.0308x over previous
//
#include <hip/hip_runtime.h>
#include <cstdint>
#include <cstddef>

typedef _Float16 f16;
typedef _Float16 f16x4 __attribute__((ext_vector_type(4)));
typedef _Float16 f16x8 __attribute__((ext_vector_type(8)));
typedef float    f32x4 __attribute__((ext_vector_type(4)));

#define NB 64
#define NN 262144   // 512*512

__device__ __forceinline__ void gload_lds16(const void* g, void* l) {
    __builtin_amdgcn_global_load_lds(
        (const __attribute__((address_space(1))) void*)g,
        (__attribute__((address_space(3))) void*)l, 16, 0, 0);
}

// prep: [0,1024) colsum partials ; [1024,1216) transW.  (cvtX eliminated)
__global__ __launch_bounds__(256, 4)
void k_pre(const float* __restrict__ adj, float* __restrict__ part,
           const float* __restrict__ W1, const float* __restrict__ W2,
           const float* __restrict__ W3, f16* __restrict__ Wt) {
    __shared__ float t[64][65];
    const int bid = blockIdx.x, tid = threadIdx.x;
    if (bid < 1024) {
        int b = bid >> 4;
        int rr0 = (bid & 15) * 32 + (tid >> 7) * 16;
        int c4 = (tid & 127) * 4;
        const float* ab = adj + (size_t)b * NN + (size_t)rr0 * 512 + c4;
        f32x4 v[16];
        #pragma unroll
        for (int i = 0; i < 16; ++i)
            v[i] = *(const f32x4*)(ab + (size_t)i * 512);
        f32x4 s = ((v[0] + v[1]) + (v[2] + v[3])) + ((v[4] + v[5]) + (v[6] + v[7]))
                + ((v[8] + v[9]) + (v[10] + v[11])) + ((v[12] + v[13]) + (v[14] + v[15]));
        int ch2 = (bid & 15) * 2 + (tid >> 7);
        *(f32x4*)&part[((size_t)b * 32 + ch2) * 512 + c4] = s;
    } else {
        int cb = bid - 1024;
        int z = cb >> 6, rem = cb & 63;
        const float* W = z == 0 ? W1 : (z == 1 ? W2 : W3);
        f16* out = Wt + (size_t)z * NN;
        int k0 = (rem >> 3) * 64, d0 = (rem & 7) * 64;
        int c = tid & 63, r4 = tid >> 6;
        #pragma unroll
        for (int s = 0; s < 16; ++s) {
            int rr = r4 + s * 4;
            t[rr][c] = W[(size_t)(k0 + rr) * 512 + d0 + c];
        }
        __syncthreads();
        int kq = (tid & 15) * 4;
        int db = tid >> 4;
        #pragma unroll
        for (int s = 0; s < 4; ++s) {
            int dd = db + s * 16;
            f16x4 o;
            #pragma unroll
            for (int q = 0; q < 4; ++q)
                o[q] = (f16)(64.f * t[kq + q][dd]);
            *(f16x4*)&out[(size_t)(d0 + dd) * 512 + k0 + kq] = o;
        }
    }
}

// A_h[b][i][j] = f16( 16 * r[b][i] * adj[b][j][i] * r[b][j] ).
// 1-D grid 4096, XCD-aligned: batch b produced on the XCD that consumes it in GEMMs.
__global__ void k_makeA(const float* __restrict__ adj, const float* __restrict__ part,
                        f16* __restrict__ A_h) {
    __shared__ float t[64][68];
    __shared__ float ri_s[64], rj_s[64];
    const int tid = threadIdx.x;
    const int bid = blockIdx.x;
    const int xcd = bid & 7, loc = bid >> 3;       // 512 blocks/XCD
    const int b = xcd * 8 + (loc >> 6);            // 8 batches/XCD (matches GEMM swizzle)
    const int tile = loc & 63;
    const int i0 = (tile >> 3) * 64, j0 = (tile & 7) * 64;
    const float* ab = adj + (size_t)b * NN;
    int trow = tid >> 4;
    int tc4  = (tid & 15) * 4;
    #pragma unroll
    for (int s = 0; s < 4; ++s) {
        int rr = trow + s * 16;
        *(f32x4*)&t[rr][tc4] = *(const f32x4*)&ab[(size_t)(j0 + rr) * 512 + i0 + tc4];
    }
    if (tid < 128) {
        int col = tid < 64 ? i0 + tid : j0 + tid - 64;
        const float* p = part + (size_t)b * 32 * 512 + col;
        float s = 0.f;
        #pragma unroll
        for (int ch = 0; ch < 32; ++ch) s += p[ch * 512];
        float rv = (s > 0.f) ? rsqrtf(s) : 0.f;
        if (tid < 64) ri_s[tid] = rv;
        else          rj_s[tid - 64] = rv;
    }
    __syncthreads();
    f16* Ab = A_h + (size_t)b * NN;
    int jq = (tid & 15) * 4;
    int ib = tid >> 4;
    #pragma unroll
    for (int s = 0; s < 4; ++s) {
        int ii = ib + s * 16;
        float ri = 16.f * ri_s[ii];
        f16x4 o;
        #pragma unroll
        for (int q = 0; q < 4; ++q)
            o[q] = (f16)(ri * t[jq + q][ii] * rj_s[jq + q]);
        *(f16x4*)&Ab[(size_t)(i0 + ii) * 512 + j0 + jq] = o;
    }
}

// G1: S1^T = (X0 @ W1)^T * oscale. X0 read f32, reg-staged cvt to f16 in LDS.
// 128x128 tile, BK=64, 4 waves; issue-early / convert-after-MFMA schedule.
__global__ __launch_bounds__(256, 2)
void gemm1_cvt(const float* __restrict__ X0, const f16* __restrict__ Wt,
               f16* __restrict__ S_t, float oscale) {
    __shared__ __align__(16) f16 Plds[2][8192];
    __shared__ __align__(16) f16 Qlds[2][8192];

    const int tid  = threadIdx.x;
    const int lane = tid & 63;
    const int wid  = tid >> 6;
    const int wm   = wid >> 1, wn = wid & 1;

    const int wg  = blockIdx.x;
    const int swz = (wg & 7) * 128 + (wg >> 3);
    const int b   = swz >> 4;
    const int tt  = swz & 15;
    const int m0  = (tt >> 2) * 128;
    const int n0  = (tt & 3) * 128;

    const float* Pb = X0 + (size_t)b * NN;
    const f16*   Qb = Wt;

    const int srow = tid >> 3;                   // 0..31
    const int sswz = (tid & 7) ^ (srow & 7);     // Q staging swizzled slot
    const int pr   = tid >> 3;                   // P row base (0..31, +32*rep)
    const int pc   = tid & 7;                    // P chunk

    const int fr = lane & 15, fs = lane >> 4, fx = fr & 7;

    auto stageQ = [&](f16* lds, int k0) {
        #pragma unroll
        for (int r = 0; r < 4; ++r) {
            const f16* src = Qb + (size_t)(n0 + r * 32 + srow) * 512 + k0 + sswz * 8;
            gload_lds16(src, lds + r * 2048 + tid * 8);
        }
    };
    float4 pv[4][2];
    auto loadP = [&](int k0) {
        #pragma unroll
        for (int rep = 0; rep < 4; ++rep) {
            const float* src = Pb + (size_t)(m0 + pr + rep * 32) * 512 + k0 + pc * 8;
            pv[rep][0] = *(const float4*)src;
            pv[rep][1] = *(const float4*)(src + 4);
        }
    };
    auto writeP = [&](f16* lds) {
        #pragma unroll
        for (int rep = 0; rep < 4; ++rep) {
            int r = pr + rep * 32;
            f16x8 o;
            o[0] = (f16)pv[rep][0].x; o[1] = (f16)pv[rep][0].y;
            o[2] = (f16)pv[rep][0].z; o[3] = (f16)pv[rep][0].w;
            o[4] = (f16)pv[rep][1].x; o[5] = (f16)pv[rep][1].y;
            o[6] = (f16)pv[rep][1].z; o[7] = (f16)pv[rep][1].w;
            *(f16x8*)(lds + r * 64 + (pc ^ (r & 7)) * 8) = o;
        }
    };

    f32x4 acc[4][4] = {};

    // prologue: tile 0
    loadP(0);
    stageQ(&Qlds[0][0], 0);
    asm volatile("s_waitcnt vmcnt(0)" ::: "memory");
    writeP(&Plds[0][0]);
    asm volatile("s_waitcnt lgkmcnt(0)" ::: "memory");
    __builtin_amdgcn_sched_barrier(0);
    __builtin_amdgcn_s_barrier();

    for (int t = 0; t < 8; ++t) {
        const int nb = t & 1;
        if (t < 7) {
            loadP((t + 1) * 64);                 // P(t+1) -> regs (in flight)
            stageQ(&Qlds[nb ^ 1][0], (t + 1) * 64);
        }
        const f16* Pl = &Plds[nb][0];
        const f16* Ql = &Qlds[nb][0];
        #pragma unroll
        for (int krep = 0; krep < 2; ++krep) {
            const int sp = ((fs + krep * 4) ^ fx) * 8;
            f16x8 af[4], bf[4];
            #pragma unroll
            for (int mi = 0; mi < 4; ++mi)
                af[mi] = *(const f16x8*)&Pl[(wm * 64 + mi * 16 + fr) * 64 + sp];
            #pragma unroll
            for (int ni = 0; ni < 4; ++ni)
                bf[ni] = *(const f16x8*)&Ql[(wn * 64 + ni * 16 + fr) * 64 + sp];
            __builtin_amdgcn_s_setprio(1);
            #pragma unroll
            for (int mi = 0; mi < 4; ++mi)
                #pragma unroll
                for (int ni = 0; ni < 4; ++ni)
                    acc[mi][ni] = __builtin_amdgcn_mfma_f32_16x16x32_f16(
                        af[mi], bf[ni], acc[mi][ni], 0, 0, 0);
            __builtin_amdgcn_s_setprio(0);
        }
        if (t < 7) {
            asm volatile("s_waitcnt vmcnt(0)" ::: "memory");   // P regs + Q lds landed
            writeP(&Plds[nb ^ 1][0]);
        }
        asm volatile("s_waitcnt lgkmcnt(0)" ::: "memory");
        __builtin_amdgcn_sched_barrier(0);
        __builtin_amdgcn_s_barrier();
    }

    const int cmb = (lane >> 4) * 4;
    #pragma unroll
    for (int mi = 0; mi < 4; ++mi) {
        #pragma unroll
        for (int ni = 0; ni < 4; ++ni) {
            const int n = n0 + wn * 64 + ni * 16 + fr;
            const int m = m0 + wm * 64 + mi * 16 + cmb;
            f16x4 o;
            #pragma unroll
            for (int q = 0; q < 4; ++q) o[q] = (f16)(acc[mi][ni][q] * oscale);
            *(f16x4*)&S_t[(size_t)b * NN + (size_t)n * 512 + m] = o;
        }
    }
}

// G2..G6: 128x128 tile, BK=64, 4 waves, 2 WG/CU, two-barrier counted-vmcnt(8),
// both-sides XOR slot swizzle. (unchanged from R9)
template<bool BIAS, bool RELU, bool OUTF32>
__global__ __launch_bounds__(256, 2)
void gemm_tn_ct(const f16* __restrict__ P, size_t pstr,
                const f16* __restrict__ Qt, size_t qstr,
                void* __restrict__ Cout, size_t cstr,
                const float* __restrict__ bias, float iscale, float oscale) {
    __shared__ __align__(16) f16 Plds[2][8192];
    __shared__ __align__(16) f16 Qlds[2][8192];

    const int tid  = threadIdx.x;
    const int lane = tid & 63;
    const int wid  = tid >> 6;
    const int wm   = wid >> 1;
    const int wn   = wid & 1;

    const int wg  = blockIdx.x;
    const int swz = (wg & 7) * 128 + (wg >> 3);
    const int b   = swz >> 4;
    const int tt  = swz & 15;
    const int m0  = (tt >> 2) * 128;
    const int n0  = (tt & 3) * 128;

    const f16* Pb = P + (size_t)b * pstr;
    const f16* Qb = Qt + (size_t)b * qstr;

    const int srow = tid >> 3;
    const int sswz = (tid & 7) ^ (srow & 7);

    const int fr  = lane & 15;
    const int fs  = lane >> 4;
    const int fx  = fr & 7;

    auto stage = [&](const f16* __restrict__ Gb, int row0, f16* lds, int k0) {
        #pragma unroll
        for (int r = 0; r < 4; ++r) {
            const f16* src = Gb + (size_t)(row0 + r * 32 + srow) * 512 + k0 + sswz * 8;
            gload_lds16(src, lds + r * 2048 + tid * 8);
        }
    };

    f32x4 acc[4][4] = {};

    stage(Pb, m0, &Plds[0][0], 0);
    stage(Qb, n0, &Qlds[0][0], 0);

    for (int t = 0; t < 8; ++t) {
        const int nb = t & 1;
        if (t < 7) {
            stage(Pb, m0, &Plds[nb ^ 1][0], (t + 1) * 64);
            stage(Qb, n0, &Qlds[nb ^ 1][0], (t + 1) * 64);
            asm volatile("s_waitcnt vmcnt(8)" ::: "memory");
        } else {
            asm volatile("s_waitcnt vmcnt(0)" ::: "memory");
        }
        __builtin_amdgcn_s_barrier();

        const f16* Pl = &Plds[nb][0];
        const f16* Ql = &Qlds[nb][0];
        #pragma unroll
        for (int krep = 0; krep < 2; ++krep) {
            const int sp = ((fs + krep * 4) ^ fx) * 8;
            f16x8 af[4], bf[4];
            #pragma unroll
            for (int mi = 0; mi < 4; ++mi)
                af[mi] = *(const f16x8*)&Pl[(wm * 64 + mi * 16 + fr) * 64 + sp];
            #pragma unroll
            for (int ni = 0; ni < 4; ++ni)
                bf[ni] = *(const f16x8*)&Ql[(wn * 64 + ni * 16 + fr) * 64 + sp];
            __builtin_amdgcn_s_setprio(1);
            #pragma unroll
            for (int mi = 0; mi < 4; ++mi)
                #pragma unroll
                for (int ni = 0; ni < 4; ++ni)
                    acc[mi][ni] = __builtin_amdgcn_mfma_f32_16x16x32_f16(
                        af[mi], bf[ni], acc[mi][ni], 0, 0, 0);
            __builtin_amdgcn_s_setprio(0);
        }
        asm volatile("s_waitcnt lgkmcnt(0)" ::: "memory");
        __builtin_amdgcn_sched_barrier(0);
        __builtin_amdgcn_s_barrier();
    }

    const int cmb = (lane >> 4) * 4;
    #pragma unroll
    for (int mi = 0; mi < 4; ++mi) {
        #pragma unroll
        for (int ni = 0; ni < 4; ++ni) {
            const int n = n0 + wn * 64 + ni * 16 + fr;
            const int m = m0 + wm * 64 + mi * 16 + cmb;
            float v[4];
            #pragma unroll
            for (int q = 0; q < 4; ++q) {
                float x = acc[mi][ni][q] * iscale;
                if (BIAS) x += bias[m + q];
                if (RELU) x = fmaxf(x, 0.f);
                v[q] = x * oscale;
            }
            if (OUTF32) {
                float* Cb = (float*)Cout + (size_t)b * cstr;
                f32x4 o; o[0] = v[0]; o[1] = v[1]; o[2] = v[2]; o[3] = v[3];
                *(f32x4*)&Cb[(size_t)n * 512 + m] = o;
            } else {
                f16* Cb = (f16*)Cout + (size_t)b * cstr;
                f16x4 o; o[0] = (f16)v[0]; o[1] = (f16)v[1]; o[2] = (f16)v[2]; o[3] = (f16)v[3];
                *(f16x4*)&Cb[(size_t)n * 512 + m] = o;
            }
        }
    }
}

extern "C" void kernel_launch(void* const* d_in, const int* in_sizes, int n_in,
                              void* d_out, int out_size, void* d_ws, size_t ws_size,
                              hipStream_t stream) {
    const float* X0  = (const float*)d_in[0];
    const float* adj = (const float*)d_in[1];
    const float* W1  = (const float*)d_in[2];
    const float* b1  = (const float*)d_in[3];
    const float* W2  = (const float*)d_in[4];
    const float* b2  = (const float*)d_in[5];
    const float* W3  = (const float*)d_in[6];
    const float* b3  = (const float*)d_in[7];

    uint8_t* ws = (uint8_t*)d_ws;
    f16* Wt1 = (f16*)(ws + 131072);                        // 3 x 512 KiB
    f16* Wt2 = Wt1 + NN;
    f16* Wt3 = Wt2 + NN;
    f16* A_h = (f16*)(ws + 131072 + (size_t)3 * NN * 2);   // 32 MiB
    f16* Xa  = A_h + (size_t)NB * NN;                      // 32 MiB (activations)
    f16* S_t = Xa + (size_t)NB * NN;                       // 32 MiB
    float* part = (float*)S_t;   // 4 MiB, aliased (S_t first written by G1, after makeA)

    k_pre  <<<dim3(1216), dim3(256), 0, stream>>>(adj, part, W1, W2, W3, Wt1);
    k_makeA<<<dim3(4096), dim3(256), 0, stream>>>(adj, part, A_h);

    // scales: X0 x1; W stored x64; A stored x16; layer2/3 activations stored x256.
    gemm1_cvt<<<dim3(1024), dim3(256), 0, stream>>>(X0, Wt1, S_t, 1.f / 64.f);

    dim3 gg(1024), gb(256);
    gemm_tn_ct<true,  true,  false><<<gg, gb, 0, stream>>>(S_t, (size_t)NN, A_h, (size_t)NN, Xa, (size_t)NN, b1, 1.f / 16.f, 1.f);
    gemm_tn_ct<false, false, false><<<gg, gb, 0, stream>>>(Xa, (size_t)NN, Wt2, (size_t)0,  S_t, (size_t)NN, nullptr, 1.f, 4.f);
    gemm_tn_ct<true,  true,  false><<<gg, gb, 0, stream>>>(S_t, (size_t)NN, A_h, (size_t)NN, Xa, (size_t)NN, b2, 1.f / 4096.f, 256.f);
    gemm_tn_ct<false, false, false><<<gg, gb, 0, stream>>>(Xa, (size_t)NN, Wt3, (size_t)0,  S_t, (size_t)NN, nullptr, 1.f, 1.f / 64.f);
    gemm_tn_ct<true,  false, true ><<<gg, gb, 0, stream>>>(S_t, (size_t)NN, A_h, (size_t)NN, d_out, (size_t)NN, b3, 1.f / 4096.f, 1.f);
}

// Round 11
// 219.581 us; speedup vs baseline: 1.0674x; 1.0355x over previous
//
#include <hip/hip_runtime.h>
#include <cstdint>
#include <cstddef>

typedef _Float16 f16;
typedef _Float16 f16x4 __attribute__((ext_vector_type(4)));
typedef _Float16 f16x8 __attribute__((ext_vector_type(8)));
typedef float    f32x4 __attribute__((ext_vector_type(4)));

#define NB 64
#define NN 262144   // 512*512

__device__ __forceinline__ void gload_lds16(const void* g, void* l) {
    __builtin_amdgcn_global_load_lds(
        (const __attribute__((address_space(1))) void*)g,
        (__attribute__((address_space(3))) void*)l, 16, 0, 0);
}

// cvtX: X_h = f16(X0), 2048 f32/block
__global__ void k_cvtX(const float* __restrict__ x, f16* __restrict__ xh) {
    size_t i = ((size_t)blockIdx.x * 256 + threadIdx.x) * 8;
    float4 v0 = *(const float4*)(x + i);
    float4 v1 = *(const float4*)(x + i + 4);
    f16x8 o;
    o[0] = (f16)v0.x; o[1] = (f16)v0.y; o[2] = (f16)v0.z; o[3] = (f16)v0.w;
    o[4] = (f16)v1.x; o[5] = (f16)v1.y; o[6] = (f16)v1.z; o[7] = (f16)v1.w;
    *(f16x8*)(xh + i) = o;
}

// prep: blocks [0,4096): A_raw transpose tiles + column-sum partials (adj read ONCE);
//       blocks [4096,4288): transW.
// A_raw[b][i][j] = f16(adj[b][j][i]);  part[b][jt][i] = sum_{jj<64} adj[b][jt*64+jj][i]
__global__ __launch_bounds__(256)
void k_prep(const float* __restrict__ adj, f16* __restrict__ A_raw,
            float* __restrict__ part,
            const float* __restrict__ W1, const float* __restrict__ W2,
            const float* __restrict__ W3, f16* __restrict__ Wt) {
    __shared__ float t[64][68];
    __shared__ float red[4][64];
    const int bid = blockIdx.x, tid = threadIdx.x;
    if (bid < 4096) {
        const int xcd = bid & 7, loc = bid >> 3;
        const int b = xcd * 8 + (loc >> 6);        // same batch->XCD map as GEMMs
        const int tile = loc & 63;
        const int i0 = (tile >> 3) * 64, j0 = (tile & 7) * 64;
        const int jt = tile & 7;
        const float* ab = adj + (size_t)b * NN;
        int trow = tid >> 4;
        int tc4  = (tid & 15) * 4;
        #pragma unroll
        for (int s = 0; s < 4; ++s) {
            int rr = trow + s * 16;
            *(f32x4*)&t[rr][tc4] = *(const f32x4*)&ab[(size_t)(j0 + rr) * 512 + i0 + tc4];
        }
        __syncthreads();
        // column-sum partial over this tile's 64 j rows
        {
            int c = tid & 63, g = tid >> 6;
            float sg = 0.f;
            #pragma unroll
            for (int s = 0; s < 16; ++s) sg += t[g * 16 + s][c];
            red[g][c] = sg;
        }
        // transpose-convert write
        f16* Ab = A_raw + (size_t)b * NN;
        int jq = (tid & 15) * 4;
        int ib = tid >> 4;
        #pragma unroll
        for (int s = 0; s < 4; ++s) {
            int ii = ib + s * 16;
            f16x4 o;
            #pragma unroll
            for (int q = 0; q < 4; ++q) o[q] = (f16)t[jq + q][ii];
            *(f16x4*)&Ab[(size_t)(i0 + ii) * 512 + j0 + jq] = o;
        }
        __syncthreads();
        if (tid < 64)
            part[((size_t)b * 8 + jt) * 512 + i0 + tid] =
                red[0][tid] + red[1][tid] + red[2][tid] + red[3][tid];
    } else {
        int cb = bid - 4096;
        int z = cb >> 6, rem = cb & 63;
        const float* W = z == 0 ? W1 : (z == 1 ? W2 : W3);
        f16* out = Wt + (size_t)z * NN;
        int k0 = (rem >> 3) * 64, d0 = (rem & 7) * 64;
        int c = tid & 63, r4 = tid >> 6;
        #pragma unroll
        for (int s = 0; s < 16; ++s) {
            int rr = r4 + s * 4;
            t[rr][c] = W[(size_t)(k0 + rr) * 512 + d0 + c];
        }
        __syncthreads();
        int kq = (tid & 15) * 4;
        int db = tid >> 4;
        #pragma unroll
        for (int s = 0; s < 4; ++s) {
            int dd = db + s * 16;
            f16x4 o;
            #pragma unroll
            for (int q = 0; q < 4; ++q)
                o[q] = (f16)(64.f * t[kq + q][dd]);
            *(f16x4*)&out[(size_t)(d0 + dd) * 512 + k0 + kq] = o;
        }
    }
}

// r[b][n] = rsqrt(sum_{jt<8} part[b][jt][n]), 0 -> 0
__global__ void k_fin(const float* __restrict__ part, float* __restrict__ r) {
    int idx = blockIdx.x * 256 + threadIdx.x;
    int b = idx >> 9, n = idx & 511;
    const float* p = part + (size_t)b * 8 * 512 + n;
    float s = 0.f;
    #pragma unroll
    for (int jt = 0; jt < 8; ++jt) s += p[jt * 512];
    r[idx] = (s > 0.f) ? rsqrtf(s) : 0.f;
}

// C[m][n] = sum_k P[m][k]*Qt[n][k]; out Ct[n][m].
// RM: x = acc*iscale*r[m] (W-GEMM: fold r_j into stored S').
// RN: x = acc*iscale*r[n] + bias[m]; relu?; *oscale (A-GEMM: fold r_i).
// 128x128 tile, BK=64, 4 waves, 2 WG/CU, counted-vmcnt(8), XOR swizzle.
template<bool BIAS, bool RELU, bool OUTF32, bool RM, bool RN>
__global__ __launch_bounds__(256, 2)
void gemm_tn_ct(const f16* __restrict__ P, size_t pstr,
                const f16* __restrict__ Qt, size_t qstr,
                void* __restrict__ Cout, size_t cstr,
                const float* __restrict__ bias, const float* __restrict__ rbuf,
                float iscale, float oscale) {
    __shared__ __align__(16) f16 Plds[2][8192];
    __shared__ __align__(16) f16 Qlds[2][8192];

    const int tid  = threadIdx.x;
    const int lane = tid & 63;
    const int wid  = tid >> 6;
    const int wm   = wid >> 1;
    const int wn   = wid & 1;

    const int wg  = blockIdx.x;
    const int swz = (wg & 7) * 128 + (wg >> 3);
    const int b   = swz >> 4;
    const int tt  = swz & 15;
    const int m0  = (tt >> 2) * 128;
    const int n0  = (tt & 3) * 128;

    const f16* Pb = P + (size_t)b * pstr;
    const f16* Qb = Qt + (size_t)b * qstr;
    const float* rs = rbuf + (size_t)b * 512;

    const int srow = tid >> 3;
    const int sswz = (tid & 7) ^ (srow & 7);

    const int fr  = lane & 15;
    const int fs  = lane >> 4;
    const int fx  = fr & 7;

    auto stage = [&](const f16* __restrict__ Gb, int row0, f16* lds, int k0) {
        #pragma unroll
        for (int r = 0; r < 4; ++r) {
            const f16* src = Gb + (size_t)(row0 + r * 32 + srow) * 512 + k0 + sswz * 8;
            gload_lds16(src, lds + r * 2048 + tid * 8);
        }
    };

    f32x4 acc[4][4] = {};

    stage(Pb, m0, &Plds[0][0], 0);
    stage(Qb, n0, &Qlds[0][0], 0);

    for (int t = 0; t < 8; ++t) {
        const int nb = t & 1;
        if (t < 7) {
            stage(Pb, m0, &Plds[nb ^ 1][0], (t + 1) * 64);
            stage(Qb, n0, &Qlds[nb ^ 1][0], (t + 1) * 64);
            asm volatile("s_waitcnt vmcnt(8)" ::: "memory");
        } else {
            asm volatile("s_waitcnt vmcnt(0)" ::: "memory");
        }
        __builtin_amdgcn_s_barrier();

        const f16* Pl = &Plds[nb][0];
        const f16* Ql = &Qlds[nb][0];
        #pragma unroll
        for (int krep = 0; krep < 2; ++krep) {
            const int sp = ((fs + krep * 4) ^ fx) * 8;
            f16x8 af[4], bf[4];
            #pragma unroll
            for (int mi = 0; mi < 4; ++mi)
                af[mi] = *(const f16x8*)&Pl[(wm * 64 + mi * 16 + fr) * 64 + sp];
            #pragma unroll
            for (int ni = 0; ni < 4; ++ni)
                bf[ni] = *(const f16x8*)&Ql[(wn * 64 + ni * 16 + fr) * 64 + sp];
            __builtin_amdgcn_s_setprio(1);
            #pragma unroll
            for (int mi = 0; mi < 4; ++mi)
                #pragma unroll
                for (int ni = 0; ni < 4; ++ni)
                    acc[mi][ni] = __builtin_amdgcn_mfma_f32_16x16x32_f16(
                        af[mi], bf[ni], acc[mi][ni], 0, 0, 0);
            __builtin_amdgcn_s_setprio(0);
        }
        asm volatile("s_waitcnt lgkmcnt(0)" ::: "memory");
        __builtin_amdgcn_sched_barrier(0);
        __builtin_amdgcn_s_barrier();
    }

    const int cmb = (lane >> 4) * 4;
    f32x4 rm4[4];
    float rn1[4];
    if (RM) {
        #pragma unroll
        for (int mi = 0; mi < 4; ++mi)
            rm4[mi] = *(const f32x4*)&rs[m0 + wm * 64 + mi * 16 + cmb];
    }
    if (RN) {
        #pragma unroll
        for (int ni = 0; ni < 4; ++ni)
            rn1[ni] = rs[n0 + wn * 64 + ni * 16 + fr];
    }
    #pragma unroll
    for (int mi = 0; mi < 4; ++mi) {
        #pragma unroll
        for (int ni = 0; ni < 4; ++ni) {
            const int n = n0 + wn * 64 + ni * 16 + fr;
            const int m = m0 + wm * 64 + mi * 16 + cmb;
            float v[4];
            #pragma unroll
            for (int q = 0; q < 4; ++q) {
                float x = acc[mi][ni][q] * iscale;
                if (RM) x *= rm4[mi][q];
                if (RN) x *= rn1[ni];
                if (BIAS) x += bias[m + q];
                if (RELU) x = fmaxf(x, 0.f);
                v[q] = x * oscale;
            }
            if (OUTF32) {
                float* Cb = (float*)Cout + (size_t)b * cstr;
                f32x4 o; o[0] = v[0]; o[1] = v[1]; o[2] = v[2]; o[3] = v[3];
                *(f32x4*)&Cb[(size_t)n * 512 + m] = o;
            } else {
                f16* Cb = (f16*)Cout + (size_t)b * cstr;
                f16x4 o; o[0] = (f16)v[0]; o[1] = (f16)v[1]; o[2] = (f16)v[2]; o[3] = (f16)v[3];
                *(f16x4*)&Cb[(size_t)n * 512 + m] = o;
            }
        }
    }
}

extern "C" void kernel_launch(void* const* d_in, const int* in_sizes, int n_in,
                              void* d_out, int out_size, void* d_ws, size_t ws_size,
                              hipStream_t stream) {
    const float* X0  = (const float*)d_in[0];
    const float* adj = (const float*)d_in[1];
    const float* W1  = (const float*)d_in[2];
    const float* b1  = (const float*)d_in[3];
    const float* W2  = (const float*)d_in[4];
    const float* b2  = (const float*)d_in[5];
    const float* W3  = (const float*)d_in[6];
    const float* b3  = (const float*)d_in[7];

    uint8_t* ws = (uint8_t*)d_ws;
    float* rbuf = (float*)ws;                              // 128 KiB
    f16* Wt1 = (f16*)(ws + 131072);                        // 3 x 512 KiB
    f16* Wt2 = Wt1 + NN;
    f16* Wt3 = Wt2 + NN;
    f16* A_raw = (f16*)(ws + 131072 + (size_t)3 * NN * 2); // 32 MiB (adj^T, f16)
    f16* Xa  = A_raw + (size_t)NB * NN;                    // 32 MiB (X / activations)
    f16* S_t = Xa + (size_t)NB * NN;                       // 32 MiB
    float* part = (float*)S_t;   // 64*8*512*4 = 1 MiB, aliased (S_t written after k_fin)

    k_prep<<<dim3(4288), dim3(256), 0, stream>>>(adj, A_raw, part, W1, W2, W3, Wt1);
    k_cvtX<<<dim3(8192), dim3(256), 0, stream>>>(X0, Xa);
    k_fin <<<dim3(128),  dim3(256), 0, stream>>>(part, rbuf);

    dim3 gg(1024), gb(256);
    // ledger: Xa holds 256^l * X_l; Wt = 64*W; S' = c_l * r_j * S_l with c1=256, c2=c3=262144.
    // G1: acc=64*S1           -> store 4*r*acc      = 256*r*S1
    gemm_tn_ct<false, false, false, true,  false><<<gg, gb, 0, stream>>>(Xa,  (size_t)NN, Wt1, (size_t)0,  S_t, (size_t)NN, nullptr, rbuf, 4.f, 1.f);
    // G2: acc=256*(A S1)/r_i  -> X1=relu(acc/256*r_n + b1), store 256*X1
    gemm_tn_ct<true,  true,  false, false, true ><<<gg, gb, 0, stream>>>(S_t, (size_t)NN, A_raw, (size_t)NN, Xa, (size_t)NN, b1, rbuf, 1.f / 256.f, 256.f);
    // G3: acc=16384*S2        -> store 16*r*acc     = 262144*r*S2
    gemm_tn_ct<false, false, false, true,  false><<<gg, gb, 0, stream>>>(Xa,  (size_t)NN, Wt2, (size_t)0,  S_t, (size_t)NN, nullptr, rbuf, 16.f, 1.f);
    // G4: acc=262144*(A S2)/r_i -> X2=relu(acc/262144*r_n + b2), store 256*X2
    gemm_tn_ct<true,  true,  false, false, true ><<<gg, gb, 0, stream>>>(S_t, (size_t)NN, A_raw, (size_t)NN, Xa, (size_t)NN, b2, rbuf, 1.f / 262144.f, 256.f);
    // G5: acc=16384*S3        -> store 16*r*acc
    gemm_tn_ct<false, false, false, true,  false><<<gg, gb, 0, stream>>>(Xa,  (size_t)NN, Wt3, (size_t)0,  S_t, (size_t)NN, nullptr, rbuf, 16.f, 1.f);
    // G6: out = acc/262144*r_n + b3  (f32)
    gemm_tn_ct<true,  false, true,  false, true ><<<gg, gb, 0, stream>>>(S_t, (size_t)NN, A_raw, (size_t)NN, d_out, (size_t)NN, b3, rbuf, 1.f / 262144.f, 1.f);
}